// Round 8
// baseline (1094.706 us; speedup 1.0000x reference)
//
#include <hip/hip_runtime.h>
#include <math.h>

#define BB 8
#define NN 1024
#define MM 1024
#define CC 512
#define SS 2048
#define KK 16
#define PH 64
#define AH 1024
#define COLS (NN * KK)
#define EPSV 1e-5f

typedef _Float16 half8 __attribute__((ext_vector_type(8)));
typedef _Float16 half4 __attribute__((ext_vector_type(4)));
typedef _Float16 half2v __attribute__((ext_vector_type(2)));
typedef float f32x4 __attribute__((ext_vector_type(4)));
typedef float f32x2 __attribute__((ext_vector_type(2)));

// ---------------------------------------------------------------------------
// global->LDS direct copy, 16B per lane. Dest is wave-uniform base + lane*16.
// ---------------------------------------------------------------------------
__device__ __forceinline__ void gl_lds16(const void* g, void* l) {
  __builtin_amdgcn_global_load_lds(
      (const __attribute__((address_space(1))) unsigned int*)g,
      (__attribute__((address_space(3))) unsigned int*)l, 16, 0, 0);
}

// Involution swizzle on LDS byte offsets: XOR bits 4-5 with bits 7-8.
__device__ __forceinline__ int swz(int x) { return x ^ (((x >> 7) & 3) << 4); }

// Stage a 128-row x 64-byte (8KB) tile into `region` (linear LDS dest,
// pre-swizzled per-lane global source so that reads with swz() see logical).
__device__ __forceinline__ void stage_tile(const char* gbase, size_t row_stride,
                                           char* region, int t) {
  const int lane = t & 63, w = t >> 6;
#pragma unroll
  for (int pass = 0; pass < 2; ++pass) {
    int d = pass * 4096 + w * 1024 + lane * 16;
    int l = swz(d);
    gl_lds16(gbase + (size_t)(l >> 6) * row_stride + (l & 63),
             region + pass * 4096 + w * 1024);
  }
}

__device__ __forceinline__ half8 frag_ld(const char* region, int rowbase, int lane) {
  int lb = (rowbase + (lane & 15)) * 64 + (lane >> 4) * 16;
  return *(const half8*)(region + swz(lb));
}

// ---------------------------------------------------------------------------
// Kernel 1: KNN (unchanged — verified).
// ---------------------------------------------------------------------------
__global__ __launch_bounds__(256) void knn_kernel(
    const float* __restrict__ pcd, const float* __restrict__ pcd_fb,
    int* __restrict__ knn) {
  __shared__ float sx[SS], sy[SS], sz[SS], ss[SS];
  const int t = threadIdx.x;
  const int b = blockIdx.x >> 8;
  const int nbase = (blockIdx.x & 255) * 4;
  for (int s = t; s < SS; s += 256) {
    float x, y, z;
    if (s < NN) {
      x = pcd[(b * 3 + 0) * NN + s];
      y = pcd[(b * 3 + 1) * NN + s];
      z = pcd[(b * 3 + 2) * NN + s];
    } else {
      int s2 = s - NN;
      x = pcd_fb[(b * 3 + 0) * MM + s2];
      y = pcd_fb[(b * 3 + 1) * MM + s2];
      z = pcd_fb[(b * 3 + 2) * MM + s2];
    }
    sx[s] = x; sy[s] = y; sz[s] = z;
    ss[s] = x * x + y * y + z * z;
  }
  __syncthreads();
  const int wv = t >> 6, lane = t & 63;
  const int n = nbase + wv;
  const float qx = sx[n], qy = sy[n], qz = sz[n];
  const float qq = qx * qx + qy * qy + qz * qz;
  float d[32];
#pragma unroll
  for (int i = 0; i < 32; ++i) {
    int s = i * 64 + lane;
    d[i] = qq - 2.0f * (qx * sx[s] + qy * sy[s] + qz * sz[s]) + ss[s];
  }
  unsigned mask = 0;
  int win = -1;
#pragma unroll
  for (int r = 0; r < 16; ++r) {
    float best = 3.4e38f;
    int bi = 0x7fffffff;
#pragma unroll
    for (int i = 0; i < 32; ++i) {
      if (!((mask >> i) & 1) && d[i] < best) { best = d[i]; bi = i * 64 + lane; }
    }
#pragma unroll
    for (int off = 32; off >= 1; off >>= 1) {
      float ov = __shfl_xor(best, off);
      int oi = __shfl_xor(bi, off);
      if (ov < best || (ov == best && oi < bi)) { best = ov; bi = oi; }
    }
    if ((bi & 63) == lane) mask |= 1u << (bi >> 6);
    if (lane == r) win = bi;
  }
  if (lane < 16) knn[((size_t)b * NN + n) * KK + lane] = win;
}

// ---------------------------------------------------------------------------
// Kernel 2: repack attn weights to fp16 (k-contiguous rows) + s1.
// ---------------------------------------------------------------------------
__global__ __launch_bounds__(256) void repack(
    const float* __restrict__ w1, const float* __restrict__ w2,
    const float* __restrict__ g, const float* __restrict__ beta,
    const float* __restrict__ m, const float* __restrict__ v,
    const float* __restrict__ b1,
    _Float16* __restrict__ w1h, _Float16* __restrict__ w2h,
    float* __restrict__ s1, float* __restrict__ t1) {
  int i = blockIdx.x * 256 + threadIdx.x;
  for (int e = i; e < AH * CC; e += gridDim.x * 256) w1h[e] = (_Float16)w1[e];
  for (int e = i; e < CC * AH; e += gridDim.x * 256) w2h[e] = (_Float16)w2[e];
  if (i < AH) {
    float sc = g[i] * rsqrtf(v[i] + EPSV);
    s1[i] = sc;
    t1[i] = (b1[i] - m[i]) * sc + beta[i];
  }
}

// ---------------------------------------------------------------------------
// Kernel 2a: W1p = W1 @ pos_w2 (fp16) and folded bias t1n = s1*(b1 + W1@pos_b2
// - m) + beta. One block per h, 64 threads.
// ---------------------------------------------------------------------------
__global__ __launch_bounds__(64) void prep_w1p(
    const float* __restrict__ aw1, const float* __restrict__ pw2,
    const float* __restrict__ pb2, const float* __restrict__ ab1,
    const float* __restrict__ ag, const float* __restrict__ abeta,
    const float* __restrict__ am, const float* __restrict__ av,
    _Float16* __restrict__ W1ph, float* __restrict__ t1n) {
  __shared__ float wrow[CC];
  const int h = blockIdx.x, p = threadIdx.x;
  for (int c = p; c < CC; c += 64) wrow[c] = aw1[(size_t)h * CC + c];
  __syncthreads();
  float acc = 0.0f;
  for (int c = 0; c < CC; ++c) acc += wrow[c] * pw2[(size_t)c * PH + p];
  W1ph[(size_t)h * PH + p] = (_Float16)acc;
  float c1p = 0.0f;
  for (int c = p; c < CC; c += 64) c1p += wrow[c] * pb2[c];
#pragma unroll
  for (int o = 32; o >= 1; o >>= 1) c1p += __shfl_xor(c1p, o);
  if (p == 0) {
    float sc = ag[h] * rsqrtf(av[h] + EPSV);
    t1n[h] = (ab1[h] + c1p - am[h]) * sc + abeta[h];
  }
}

// ---------------------------------------------------------------------------
// Kernel 2b: per-batch transpose fusion_feat [c][s] -> FT32 [s][c] f32 AND
// FT16 [s][c] fp16 (B-matrix for the Y-GEMM).
// ---------------------------------------------------------------------------
__global__ __launch_bounds__(256) void transpose_feat(
    int b, const float* __restrict__ feat, const float* __restrict__ feat_fb,
    float* __restrict__ FT32, _Float16* __restrict__ FT16) {
  __shared__ float tl[64][65];
  const int t = threadIdx.x;
  const int s0 = (blockIdx.x & 31) * 64;
  const int c0 = (blockIdx.x >> 5) * 64;
  const float* src = (s0 < NN) ? feat + (size_t)b * CC * NN + s0
                               : feat_fb + (size_t)b * CC * MM + (s0 - NN);
  const int sl = t & 63, w4 = t >> 6;
#pragma unroll
  for (int r = 0; r < 16; ++r) {
    int cl = w4 * 16 + r;
    tl[sl][cl] = src[(size_t)(c0 + cl) * NN + sl];
  }
  __syncthreads();
#pragma unroll
  for (int r = 0; r < 16; ++r) {
    int sl2 = w4 * 16 + r;
    float vv = tl[sl2][sl];
    FT32[((size_t)s0 + sl2) * CC + c0 + sl] = vv;
    FT16[((size_t)s0 + sl2) * CC + c0 + sl] = (_Float16)vv;
  }
}

// ---------------------------------------------------------------------------
// Kernel 3: gather + pos MLP. Writes h1g [col][64] fp16 and V=[col][c] f32.
// (X is no longer materialized — folded into Y1/Z path.)
// ---------------------------------------------------------------------------
__global__ __launch_bounds__(256) void build_xv(
    int b,
    const float* __restrict__ pcd, const float* __restrict__ pcd_fb,
    const float* __restrict__ FT32,
    const float* __restrict__ pw1, const float* __restrict__ pb1,
    const float* __restrict__ pg, const float* __restrict__ pbeta,
    const float* __restrict__ pm, const float* __restrict__ pv,
    const float* __restrict__ pw2, const float* __restrict__ pb2,
    const int* __restrict__ knn, _Float16* __restrict__ h1g,
    float* __restrict__ Vp) {
  __shared__ int idx_sh[KK];
  __shared__ float prel[3][KK];
  __shared__ float h1r[KK][PH + 4];
  __shared__ float pe_lds[KK][520];
  const int t = threadIdx.x;
  const int n = blockIdx.x;
  if (t < KK) idx_sh[t] = knn[(size_t)b * COLS + n * KK + t];
  __syncthreads();
  if (t < 3 * KK) {
    int dd = t >> 4, k = t & 15;
    int s = idx_sh[k];
    float gp = (s < NN) ? pcd[(b * 3 + dd) * NN + s]
                        : pcd_fb[(b * 3 + dd) * MM + (s - NN)];
    prel[dd][k] = pcd[(b * 3 + dd) * NN + n] - gp;
  }
  __syncthreads();
  for (int e = t; e < PH * KK; e += 256) {
    int h = e >> 4, k = e & 15;
    float val = pb1[h] + pw1[h * 3 + 0] * prel[0][k] + pw1[h * 3 + 1] * prel[1][k]
              + pw1[h * 3 + 2] * prel[2][k];
    float sc = pg[h] * rsqrtf(pv[h] + EPSV);
    val = (val - pm[h]) * sc + pbeta[h];
    h1r[k][h] = fmaxf(val, 0.0f);
  }
  __syncthreads();
  // h1 -> global fp16 [col][64]
  for (int e = t; e < KK * PH; e += 256) {
    int k = e >> 6, h = e & 63;
    h1g[((size_t)n * KK + k) * PH + h] = (_Float16)h1r[k][h];
  }
  // ---- Phase A: pe[k] for channels c0=t and c1=t+256 -----------------------
  float pe0[KK], pe1[KK];
#pragma unroll
  for (int k = 0; k < KK; ++k) { pe0[k] = 0.0f; pe1[k] = 0.0f; }
  const float* w2r0 = pw2 + (size_t)t * PH;
  const float* w2r1 = pw2 + (size_t)(t + 256) * PH;
  for (int hq = 0; hq < PH / 4; ++hq) {
    f32x4 wa = *(const f32x4*)(w2r0 + hq * 4);
    f32x4 wb = *(const f32x4*)(w2r1 + hq * 4);
#pragma unroll
    for (int k = 0; k < KK; ++k) {
      f32x4 hk = *(const f32x4*)&h1r[k][hq * 4];  // wave-uniform -> broadcast
      pe0[k] += wa.x * hk.x + wa.y * hk.y + wa.z * hk.z + wa.w * hk.w;
      pe1[k] += wb.x * hk.x + wb.y * hk.y + wb.z * hk.z + wb.w * hk.w;
    }
  }
  {
    float bb0 = pb2[t], bb1 = pb2[t + 256];
#pragma unroll
    for (int k = 0; k < KK; ++k) {
      pe_lds[k][t] = pe0[k] + bb0;
      pe_lds[k][t + 256] = pe1[k] + bb1;
    }
  }
  __syncthreads();
  // ---- Phase B: coalesced V stream ----------------------------------------
  for (int k = 0; k < KK; ++k) {
    int s = idx_sh[k];
    f32x2 gfv = *(const f32x2*)(FT32 + (size_t)s * CC + 2 * t);
    f32x2 pe2 = *(const f32x2*)&pe_lds[k][2 * t];
    size_t col = (size_t)n * KK + k;
    f32x2 vo;
    vo[0] = gfv[0] + pe2[0];
    vo[1] = gfv[1] + pe2[1];
    *(f32x2*)(Vp + col * CC + 2 * t) = vo;
  }
}

// ---------------------------------------------------------------------------
// Kernel 4a: Y1 = W1 @ fusion_feat (no bias/bn). Output [s][h] fp16 via
// direct half4 stores. Grid (SS/128, AH/128).
// ---------------------------------------------------------------------------
__global__ __launch_bounds__(256) void ygemm_f16(
    const _Float16* __restrict__ Wh, const _Float16* __restrict__ FT16,
    _Float16* __restrict__ Y1) {
  __shared__ char lds[16384];
  char* As = lds;
  char* Bs = lds + 8192;
  const int t = threadIdx.x, lane = t & 63, w = t >> 6;
  const int wr = w >> 1, wc = w & 1;
  const int h0 = blockIdx.y * 128;
  const int col0 = blockIdx.x * 128;
  f32x4 acc[4][4];
  f32x4 zz = {0.f, 0.f, 0.f, 0.f};
#pragma unroll
  for (int m = 0; m < 4; ++m)
#pragma unroll
    for (int n = 0; n < 4; ++n) acc[m][n] = zz;
  for (int s = 0; s < CC / 32; ++s) {
    const int k0 = s * 32;
    stage_tile((const char*)(Wh + (size_t)h0 * CC + k0), CC * 2, As, t);
    stage_tile((const char*)(FT16 + (size_t)col0 * CC + k0), CC * 2, Bs, t);
    __syncthreads();
    half8 a[4], bf[4];
#pragma unroll
    for (int m = 0; m < 4; ++m) a[m] = frag_ld(As, wr * 64 + m * 16, lane);
#pragma unroll
    for (int n = 0; n < 4; ++n) bf[n] = frag_ld(Bs, wc * 64 + n * 16, lane);
#pragma unroll
    for (int m = 0; m < 4; ++m)
#pragma unroll
      for (int n = 0; n < 4; ++n)
        acc[m][n] = __builtin_amdgcn_mfma_f32_16x16x32_f16(a[m], bf[n], acc[m][n], 0, 0, 0);
    __syncthreads();
  }
#pragma unroll
  for (int m = 0; m < 4; ++m)
#pragma unroll
    for (int n = 0; n < 4; ++n) {
      int col = col0 + wc * 64 + n * 16 + (lane & 15);
      int hb = h0 + wr * 64 + m * 16 + (lane >> 4) * 4;
      half4 p;
#pragma unroll
      for (int r = 0; r < 4; ++r) p[r] = (_Float16)acc[m][n][r];
      *(half4*)(Y1 + (size_t)col * AH + hb) = p;
    }
}

// ---------------------------------------------------------------------------
// Kernel 4b: Z-GEMM (K=64): A1R = relu(s1*(Y1[n] - Y1[s] + W1p@h1) + t1n).
// Gathers Y1 rows in the epilogue (L2/L3-resident). Grid (COLS/128, AH/128).
// ---------------------------------------------------------------------------
__global__ __launch_bounds__(256) void zgemm_f16(
    int b, const _Float16* __restrict__ W1ph, const _Float16* __restrict__ h1g,
    const _Float16* __restrict__ Y1, const int* __restrict__ knn,
    const float* __restrict__ s1, const float* __restrict__ t1n,
    _Float16* __restrict__ A1Rp) {
  __shared__ char lds[16384];
  __shared__ int idx_sh2[128];
  char* As = lds;
  char* Bs = lds + 8192;
  const int t = threadIdx.x, lane = t & 63, w = t >> 6;
  const int wr = w >> 1, wc = w & 1;
  const int h0 = blockIdx.y * 128;
  const int col0 = blockIdx.x * 128;
  if (t < 128) idx_sh2[t] = knn[(size_t)b * COLS + col0 + t];
  f32x4 acc[4][4];
  f32x4 zz = {0.f, 0.f, 0.f, 0.f};
#pragma unroll
  for (int m = 0; m < 4; ++m)
#pragma unroll
    for (int n = 0; n < 4; ++n) acc[m][n] = zz;
#pragma unroll
  for (int s = 0; s < 2; ++s) {
    const int k0 = s * 32;
    stage_tile((const char*)(W1ph + (size_t)h0 * PH + k0), PH * 2, As, t);
    stage_tile((const char*)(h1g + (size_t)col0 * PH + k0), PH * 2, Bs, t);
    __syncthreads();
    half8 a[4], bf[4];
#pragma unroll
    for (int m = 0; m < 4; ++m) a[m] = frag_ld(As, wr * 64 + m * 16, lane);
#pragma unroll
    for (int n = 0; n < 4; ++n) bf[n] = frag_ld(Bs, wc * 64 + n * 16, lane);
#pragma unroll
    for (int m = 0; m < 4; ++m)
#pragma unroll
      for (int n = 0; n < 4; ++n)
        acc[m][n] = __builtin_amdgcn_mfma_f32_16x16x32_f16(a[m], bf[n], acc[m][n], 0, 0, 0);
    __syncthreads();
  }
#pragma unroll
  for (int m = 0; m < 4; ++m) {
    int hb = h0 + wr * 64 + m * 16 + (lane >> 4) * 4;
    f32x4 s4 = *(const f32x4*)(s1 + hb);
    f32x4 t4 = *(const f32x4*)(t1n + hb);
#pragma unroll
    for (int n = 0; n < 4; ++n) {
      int j = wc * 64 + n * 16 + (lane & 15);
      int col = col0 + j;
      int sidx = idx_sh2[j];
      half4 yq4 = *(const half4*)(Y1 + (size_t)(col >> 4) * AH + hb);
      half4 ys4 = *(const half4*)(Y1 + (size_t)sidx * AH + hb);
      half4 p;
#pragma unroll
      for (int r = 0; r < 4; ++r) {
        float pre = acc[m][n][r] + (float)yq4[r] - (float)ys4[r];
        p[r] = (_Float16)fmaxf(pre * s4[r] + t4[r], 0.0f);
      }
      *(half4*)(A1Rp + (size_t)col * AH + hb) = p;
    }
  }
}

// ---------------------------------------------------------------------------
// Kernel 5: gemm2 = W2 @ A1R via f16 MFMA; fused softmax(K=16) + V-weighted
// sum epilogue. (unchanged — verified)
// ---------------------------------------------------------------------------
__global__ __launch_bounds__(256) void gemm2_f16(
    int b, const _Float16* __restrict__ Wh, const _Float16* __restrict__ A1Rp,
    const float* __restrict__ Vp, float* __restrict__ out) {
  __shared__ char lds[16384];
  char* As = lds;
  char* Bs = lds + 8192;
  const int t = threadIdx.x, lane = t & 63, w = t >> 6;
  const int wr = w >> 1, wc = w & 1;
  const int c0 = blockIdx.y * 128;
  const int col0 = blockIdx.x * 128;
  f32x4 acc[4][4];
  f32x4 zz = {0.f, 0.f, 0.f, 0.f};
#pragma unroll
  for (int m = 0; m < 4; ++m)
#pragma unroll
    for (int n = 0; n < 4; ++n) acc[m][n] = zz;
  for (int s = 0; s < AH / 32; ++s) {
    const int k0 = s * 32;
    stage_tile((const char*)(Wh + (size_t)c0 * AH + k0), AH * 2, As, t);
    stage_tile((const char*)(A1Rp + (size_t)col0 * AH + k0), AH * 2, Bs, t);
    __syncthreads();
    half8 a[4], bf[4];
#pragma unroll
    for (int m = 0; m < 4; ++m) a[m] = frag_ld(As, wr * 64 + m * 16, lane);
#pragma unroll
    for (int n = 0; n < 4; ++n) bf[n] = frag_ld(Bs, wc * 64 + n * 16, lane);
#pragma unroll
    for (int m = 0; m < 4; ++m)
#pragma unroll
      for (int n = 0; n < 4; ++n)
        acc[m][n] = __builtin_amdgcn_mfma_f32_16x16x32_f16(a[m], bf[n], acc[m][n], 0, 0, 0);
    __syncthreads();
  }
#pragma unroll
  for (int m = 0; m < 4; ++m)
#pragma unroll
    for (int n = 0; n < 4; ++n) {
      int cg2 = col0 + wc * 64 + n * 16 + (lane & 15);
      int nq = cg2 >> 4;
      int cbase = c0 + wr * 64 + m * 16 + (lane >> 4) * 4;
      f32x4 v4 = *(const f32x4*)(Vp + (size_t)cg2 * CC + cbase);
#pragma unroll
      for (int r = 0; r < 4; ++r) {
        float e = __expf(acc[m][n][r]);
        float se = e;
#pragma unroll
        for (int o = 8; o >= 1; o >>= 1) se += __shfl_xor(se, o);
        float te = e * v4[r];
#pragma unroll
        for (int o = 8; o >= 1; o >>= 1) te += __shfl_xor(te, o);
        if ((lane & 15) == 0)
          out[((size_t)b * CC + cbase + r) * NN + nq] = __fdividef(te, se);
      }
    }
}

// ---------------------------------------------------------------------------
extern "C" void kernel_launch(void* const* d_in, const int* in_sizes, int n_in,
                              void* d_out, int out_size, void* d_ws, size_t ws_size,
                              hipStream_t stream) {
  const float* pcd     = (const float*)d_in[0];
  const float* feat    = (const float*)d_in[1];
  const float* pcd_fb  = (const float*)d_in[2];
  const float* feat_fb = (const float*)d_in[3];
  const float* pw1     = (const float*)d_in[4];
  const float* pb1     = (const float*)d_in[5];
  const float* pg      = (const float*)d_in[6];
  const float* pbeta   = (const float*)d_in[7];
  const float* pm      = (const float*)d_in[8];
  const float* pv      = (const float*)d_in[9];
  const float* pw2     = (const float*)d_in[10];
  const float* pb2     = (const float*)d_in[11];
  const float* aw1     = (const float*)d_in[12];
  const float* ab1     = (const float*)d_in[13];
  const float* ag      = (const float*)d_in[14];
  const float* abeta   = (const float*)d_in[15];
  const float* am      = (const float*)d_in[16];
  const float* av      = (const float*)d_in[17];
  const float* aw2     = (const float*)d_in[18];
  const float* ab2     = (const float*)d_in[19];
  (void)ab2;  // cancels in softmax
  float* out = (float*)d_out;

  char* ws = (char*)d_ws;
  size_t off = 0;
  int* idx_ws = (int*)(ws + off);        off += (size_t)BB * NN * KK * sizeof(int);
  _Float16* W1h = (_Float16*)(ws + off); off += (size_t)AH * CC * 2;
  _Float16* W2h = (_Float16*)(ws + off); off += (size_t)CC * AH * 2;
  _Float16* W1ph = (_Float16*)(ws + off); off += (size_t)AH * PH * 2;
  float* s1 = (float*)(ws + off);        off += AH * sizeof(float);
  float* t1 = (float*)(ws + off);        off += AH * sizeof(float);
  float* t1n = (float*)(ws + off);       off += AH * sizeof(float);
  off = (off + 255) & ~(size_t)255;
  float* FT32 = (float*)(ws + off);       off += (size_t)SS * CC * 4;      //  4.2 MB
  _Float16* FT16 = (_Float16*)(ws + off); off += (size_t)SS * CC * 2;      //  2.1 MB
  _Float16* h1g = (_Float16*)(ws + off);  off += (size_t)COLS * PH * 2;    //  2.1 MB
  _Float16* Y1 = (_Float16*)(ws + off);   off += (size_t)SS * AH * 2;      //  4.2 MB
  _Float16* A1Rp = (_Float16*)(ws + off); off += (size_t)COLS * AH * 2;    // 33.6 MB
  float* Vp = (float*)(ws + off);         off += (size_t)COLS * CC * 4;    // 33.6 MB

  knn_kernel<<<dim3(BB * NN / 4), 256, 0, stream>>>(pcd, pcd_fb, idx_ws);
  repack<<<dim3(512), 256, 0, stream>>>(aw1, aw2, ag, abeta, am, av, ab1,
                                        W1h, W2h, s1, t1);
  prep_w1p<<<dim3(AH), 64, 0, stream>>>(aw1, pw2, pb2, ab1, ag, abeta, am, av,
                                        W1ph, t1n);
  for (int b = 0; b < BB; ++b) {
    transpose_feat<<<dim3(256), 256, 0, stream>>>(b, feat, feat_fb, FT32, FT16);
    build_xv<<<dim3(NN), 256, 0, stream>>>(
        b, pcd, pcd_fb, FT32,
        pw1, pb1, pg, pbeta, pm, pv, pw2, pb2, idx_ws, h1g, Vp);
    ygemm_f16<<<dim3(SS / 128, AH / 128), 256, 0, stream>>>(W1h, FT16, Y1);
    zgemm_f16<<<dim3(COLS / 128, AH / 128), 256, 0, stream>>>(
        b, W1ph, h1g, Y1, idx_ws, s1, t1n, A1Rp);
    gemm2_f16<<<dim3(COLS / 128, CC / 128), 256, 0, stream>>>(b, W2h, A1Rp, Vp, out);
  }
}

// Round 10
// 1010.437 us; speedup vs baseline: 1.0834x; 1.0834x over previous
//
#include <hip/hip_runtime.h>
#include <math.h>

#define BB 8
#define NN 1024
#define MM 1024
#define CC 512
#define SS 2048
#define KK 16
#define PH 64
#define AH 1024
#define COLS (NN * KK)
#define EPSV 1e-5f

typedef _Float16 half8 __attribute__((ext_vector_type(8)));
typedef _Float16 half4 __attribute__((ext_vector_type(4)));
typedef float f32x4 __attribute__((ext_vector_type(4)));
typedef float f32x2 __attribute__((ext_vector_type(2)));

// ---------------------------------------------------------------------------
// global->LDS direct copy, 16B per lane. Dest is wave-uniform base + lane*16.
// ---------------------------------------------------------------------------
__device__ __forceinline__ void gl_lds16(const void* g, void* l) {
  __builtin_amdgcn_global_load_lds(
      (const __attribute__((address_space(1))) unsigned int*)g,
      (__attribute__((address_space(3))) unsigned int*)l, 16, 0, 0);
}

// Involution swizzle on LDS byte offsets: XOR bits 4-5 with bits 7-8.
__device__ __forceinline__ int swz(int x) { return x ^ (((x >> 7) & 3) << 4); }

// Stage a 128-row x 64-byte (8KB) tile into `region` (linear LDS dest,
// pre-swizzled per-lane global source so that reads with swz() see logical).
__device__ __forceinline__ void stage_tile(const char* gbase, size_t row_stride,
                                           char* region, int t) {
  const int lane = t & 63, w = t >> 6;
#pragma unroll
  for (int pass = 0; pass < 2; ++pass) {
    int d = pass * 4096 + w * 1024 + lane * 16;
    int l = swz(d);
    gl_lds16(gbase + (size_t)(l >> 6) * row_stride + (l & 63),
             region + pass * 4096 + w * 1024);
  }
}

__device__ __forceinline__ half8 frag_ld(const char* region, int rowbase, int lane) {
  int lb = (rowbase + (lane & 15)) * 64 + (lane >> 4) * 16;
  return *(const half8*)(region + swz(lb));
}

// ---------------------------------------------------------------------------
// Kernel 1: KNN (unchanged — verified).
// ---------------------------------------------------------------------------
__global__ __launch_bounds__(256) void knn_kernel(
    const float* __restrict__ pcd, const float* __restrict__ pcd_fb,
    int* __restrict__ knn) {
  __shared__ float sx[SS], sy[SS], sz[SS], ss[SS];
  const int t = threadIdx.x;
  const int b = blockIdx.x >> 8;
  const int nbase = (blockIdx.x & 255) * 4;
  for (int s = t; s < SS; s += 256) {
    float x, y, z;
    if (s < NN) {
      x = pcd[(b * 3 + 0) * NN + s];
      y = pcd[(b * 3 + 1) * NN + s];
      z = pcd[(b * 3 + 2) * NN + s];
    } else {
      int s2 = s - NN;
      x = pcd_fb[(b * 3 + 0) * MM + s2];
      y = pcd_fb[(b * 3 + 1) * MM + s2];
      z = pcd_fb[(b * 3 + 2) * MM + s2];
    }
    sx[s] = x; sy[s] = y; sz[s] = z;
    ss[s] = x * x + y * y + z * z;
  }
  __syncthreads();
  const int wv = t >> 6, lane = t & 63;
  const int n = nbase + wv;
  const float qx = sx[n], qy = sy[n], qz = sz[n];
  const float qq = qx * qx + qy * qy + qz * qz;
  float d[32];
#pragma unroll
  for (int i = 0; i < 32; ++i) {
    int s = i * 64 + lane;
    d[i] = qq - 2.0f * (qx * sx[s] + qy * sy[s] + qz * sz[s]) + ss[s];
  }
  unsigned mask = 0;
  int win = -1;
#pragma unroll
  for (int r = 0; r < 16; ++r) {
    float best = 3.4e38f;
    int bi = 0x7fffffff;
#pragma unroll
    for (int i = 0; i < 32; ++i) {
      if (!((mask >> i) & 1) && d[i] < best) { best = d[i]; bi = i * 64 + lane; }
    }
#pragma unroll
    for (int off = 32; off >= 1; off >>= 1) {
      float ov = __shfl_xor(best, off);
      int oi = __shfl_xor(bi, off);
      if (ov < best || (ov == best && oi < bi)) { best = ov; bi = oi; }
    }
    if ((bi & 63) == lane) mask |= 1u << (bi >> 6);
    if (lane == r) win = bi;
  }
  if (lane < 16) knn[((size_t)b * NN + n) * KK + lane] = win;
}

// ---------------------------------------------------------------------------
// Kernel 2: repack weights to fp16 (W1, W2, pos_w2) + s1/t1.
// ---------------------------------------------------------------------------
__global__ __launch_bounds__(256) void repack(
    const float* __restrict__ w1, const float* __restrict__ w2,
    const float* __restrict__ pw2,
    const float* __restrict__ g, const float* __restrict__ beta,
    const float* __restrict__ m, const float* __restrict__ v,
    const float* __restrict__ b1,
    _Float16* __restrict__ w1h, _Float16* __restrict__ w2h,
    _Float16* __restrict__ pw2h,
    float* __restrict__ s1, float* __restrict__ t1) {
  int i = blockIdx.x * 256 + threadIdx.x;
  for (int e = i; e < AH * CC; e += gridDim.x * 256) w1h[e] = (_Float16)w1[e];
  for (int e = i; e < CC * AH; e += gridDim.x * 256) w2h[e] = (_Float16)w2[e];
  for (int e = i; e < CC * PH; e += gridDim.x * 256) pw2h[e] = (_Float16)pw2[e];
  if (i < AH) {
    float sc = g[i] * rsqrtf(v[i] + EPSV);
    s1[i] = sc;
    t1[i] = (b1[i] - m[i]) * sc + beta[i];
  }
}

// ---------------------------------------------------------------------------
// Kernel 2a: W1p = W1 @ pos_w2 (fp16) and t1n = s1*(b1 + W1@pos_b2 - m) + beta.
// (unchanged — verified round 8)
// ---------------------------------------------------------------------------
__global__ __launch_bounds__(64) void prep_w1p(
    const float* __restrict__ aw1, const float* __restrict__ pw2,
    const float* __restrict__ pb2, const float* __restrict__ ab1,
    const float* __restrict__ ag, const float* __restrict__ abeta,
    const float* __restrict__ am, const float* __restrict__ av,
    _Float16* __restrict__ W1ph, float* __restrict__ t1n) {
  __shared__ float wrow[CC];
  const int h = blockIdx.x, p = threadIdx.x;
  for (int c = p; c < CC; c += 64) wrow[c] = aw1[(size_t)h * CC + c];
  __syncthreads();
  float acc = 0.0f;
  for (int c = 0; c < CC; ++c) acc += wrow[c] * pw2[(size_t)c * PH + p];
  W1ph[(size_t)h * PH + p] = (_Float16)acc;
  float c1p = 0.0f;
  for (int c = p; c < CC; c += 64) c1p += wrow[c] * pb2[c];
#pragma unroll
  for (int o = 32; o >= 1; o >>= 1) c1p += __shfl_xor(c1p, o);
  if (p == 0) {
    float sc = ag[h] * rsqrtf(av[h] + EPSV);
    t1n[h] = (ab1[h] + c1p - am[h]) * sc + abeta[h];
  }
}

// ---------------------------------------------------------------------------
// Kernel 2b: per-batch transpose fusion_feat [c][s] -> FT32 [s][c] f32 AND
// FT16 [s][c] fp16. (unchanged — verified)
// ---------------------------------------------------------------------------
__global__ __launch_bounds__(256) void transpose_feat(
    int b, const float* __restrict__ feat, const float* __restrict__ feat_fb,
    float* __restrict__ FT32, _Float16* __restrict__ FT16) {
  __shared__ float tl[64][65];
  const int t = threadIdx.x;
  const int s0 = (blockIdx.x & 31) * 64;
  const int c0 = (blockIdx.x >> 5) * 64;
  const float* src = (s0 < NN) ? feat + (size_t)b * CC * NN + s0
                               : feat_fb + (size_t)b * CC * MM + (s0 - NN);
  const int sl = t & 63, w4 = t >> 6;
#pragma unroll
  for (int r = 0; r < 16; ++r) {
    int cl = w4 * 16 + r;
    tl[sl][cl] = src[(size_t)(c0 + cl) * NN + sl];
  }
  __syncthreads();
#pragma unroll
  for (int r = 0; r < 16; ++r) {
    int sl2 = w4 * 16 + r;
    float vv = tl[sl2][sl];
    FT32[((size_t)s0 + sl2) * CC + c0 + sl] = vv;
    FT16[((size_t)s0 + sl2) * CC + c0 + sl] = (_Float16)vv;
  }
}

// ---------------------------------------------------------------------------
// Kernel 3: h1 only (pos MLP layer 1 + BN + ReLU), fp16 out [col][64].
// 4 queries per block (one per wave).
// ---------------------------------------------------------------------------
__global__ __launch_bounds__(256) void build_h1(
    int b, const float* __restrict__ pcd, const float* __restrict__ pcd_fb,
    const float* __restrict__ pw1, const float* __restrict__ pb1,
    const float* __restrict__ pg, const float* __restrict__ pbeta,
    const float* __restrict__ pm, const float* __restrict__ pv,
    const int* __restrict__ knn, _Float16* __restrict__ h1g) {
  __shared__ float prel_s[4][3][KK];
  __shared__ int idx_s[4][KK];
  const int t = threadIdx.x, wv = t >> 6, lane = t & 63;
  const int n = blockIdx.x * 4 + wv;
  if (lane < KK) idx_s[wv][lane] = knn[(size_t)b * COLS + n * KK + lane];
  __syncthreads();
  if (lane < 48) {
    int dd = lane >> 4, k = lane & 15;
    int s = idx_s[wv][k];
    float gp = (s < NN) ? pcd[(b * 3 + dd) * NN + s]
                        : pcd_fb[(b * 3 + dd) * MM + (s - NN)];
    prel_s[wv][dd][k] = pcd[(b * 3 + dd) * NN + n] - gp;
  }
  __syncthreads();
  const int h = lane;
  const float w0 = pw1[h * 3 + 0], w1v = pw1[h * 3 + 1], w2v = pw1[h * 3 + 2];
  const float sc = pg[h] * rsqrtf(pv[h] + EPSV);
  const float sh = (pb1[h] - pm[h]) * sc + pbeta[h];
#pragma unroll
  for (int k = 0; k < KK; ++k) {
    float val = w0 * prel_s[wv][0][k] + w1v * prel_s[wv][1][k]
              + w2v * prel_s[wv][2][k];
    float hv = fmaxf(val * sc + sh, 0.0f);
    h1g[((size_t)n * KK + k) * PH + h] = (_Float16)hv;
  }
}

// ---------------------------------------------------------------------------
// Kernel 4a: Y1 = W1 @ fusion_feat, output [s][AH] fp16 via the verified
// LDS-transpose epilogue (coalesced half8 stores). Grid (SS/128, AH/128).
// ---------------------------------------------------------------------------
__global__ __launch_bounds__(256) void ygemm_f16(
    const _Float16* __restrict__ Wh, const _Float16* __restrict__ FT16,
    _Float16* __restrict__ Y1) {
  __shared__ char lds[34816];
  char* As = lds;
  char* Bs = lds + 8192;
  const int t = threadIdx.x, lane = t & 63, w = t >> 6;
  const int wr = w >> 1, wc = w & 1;
  const int h0 = blockIdx.y * 128;
  const int col0 = blockIdx.x * 128;
  f32x4 acc[4][4];
  f32x4 zz = {0.f, 0.f, 0.f, 0.f};
#pragma unroll
  for (int m = 0; m < 4; ++m)
#pragma unroll
    for (int n = 0; n < 4; ++n) acc[m][n] = zz;
  for (int s = 0; s < CC / 32; ++s) {
    const int k0 = s * 32;
    stage_tile((const char*)(Wh + (size_t)h0 * CC + k0), CC * 2, As, t);
    stage_tile((const char*)(FT16 + (size_t)col0 * CC + k0), CC * 2, Bs, t);
    __syncthreads();
    half8 a[4], bf[4];
#pragma unroll
    for (int m = 0; m < 4; ++m) a[m] = frag_ld(As, wr * 64 + m * 16, lane);
#pragma unroll
    for (int n = 0; n < 4; ++n) bf[n] = frag_ld(Bs, wc * 64 + n * 16, lane);
#pragma unroll
    for (int m = 0; m < 4; ++m)
#pragma unroll
      for (int n = 0; n < 4; ++n)
        acc[m][n] = __builtin_amdgcn_mfma_f32_16x16x32_f16(a[m], bf[n], acc[m][n], 0, 0, 0);
    __syncthreads();
  }
  char* tb = lds + w * 8704;
#pragma unroll
  for (int m = 0; m < 4; ++m) {
#pragma unroll
    for (int n = 0; n < 4; ++n) {
      half4 p;
#pragma unroll
      for (int r = 0; r < 4; ++r) p[r] = (_Float16)acc[m][n][r];
      int col_l = n * 16 + (lane & 15);
      *(half4*)(tb + col_l * 136 + (m * 16 + (lane >> 4) * 4) * 2) = p;
    }
  }
  __syncthreads();
  char* dstbase = (char*)Y1 + (size_t)(h0 + wr * 64) * 2;
#pragma unroll
  for (int pass = 0; pass < 8; ++pass) {
    int col_l = (lane >> 3) + pass * 8;
    int chunk = lane & 7;
    *(half8*)(dstbase + (size_t)(col0 + wc * 64 + col_l) * (AH * 2) + chunk * 16) =
        *(const half8*)(tb + col_l * 136 + chunk * 16);
  }
}

// ---------------------------------------------------------------------------
// Kernel 4b: PE-GEMM (K=64): V[c][col] = pw2@h1 + pb2[c] + FT32[s(col)][c].
// Stores f32 scalar, lanes contiguous in col (coalesced 64B runs).
// Grid (COLS/128, CC/128).
// ---------------------------------------------------------------------------
__global__ __launch_bounds__(256) void pegemm_f16(
    int b, const _Float16* __restrict__ pw2h, const _Float16* __restrict__ h1g,
    const float* __restrict__ FT32, const float* __restrict__ pb2,
    const int* __restrict__ knn, float* __restrict__ Vp) {
  __shared__ char lds[16384];
  __shared__ int idx_sh2[128];
  char* As = lds;
  char* Bs = lds + 8192;
  const int t = threadIdx.x, lane = t & 63, w = t >> 6;
  const int wr = w >> 1, wc = w & 1;
  const int c0 = blockIdx.y * 128;
  const int col0 = blockIdx.x * 128;
  if (t < 128) idx_sh2[t] = knn[(size_t)b * COLS + col0 + t];
  f32x4 acc[4][4];
  f32x4 zz = {0.f, 0.f, 0.f, 0.f};
#pragma unroll
  for (int m = 0; m < 4; ++m)
#pragma unroll
    for (int n = 0; n < 4; ++n) acc[m][n] = zz;
#pragma unroll
  for (int s = 0; s < 2; ++s) {
    const int k0 = s * 32;
    stage_tile((const char*)(pw2h + (size_t)c0 * PH + k0), PH * 2, As, t);
    stage_tile((const char*)(h1g + (size_t)col0 * PH + k0), PH * 2, Bs, t);
    __syncthreads();
    half8 a[4], bf[4];
#pragma unroll
    for (int m = 0; m < 4; ++m) a[m] = frag_ld(As, wr * 64 + m * 16, lane);
#pragma unroll
    for (int n = 0; n < 4; ++n) bf[n] = frag_ld(Bs, wc * 64 + n * 16, lane);
#pragma unroll
    for (int m = 0; m < 4; ++m)
#pragma unroll
      for (int n = 0; n < 4; ++n)
        acc[m][n] = __builtin_amdgcn_mfma_f32_16x16x32_f16(a[m], bf[n], acc[m][n], 0, 0, 0);
    __syncthreads();
  }
#pragma unroll
  for (int m = 0; m < 4; ++m) {
    int cb = c0 + wr * 64 + m * 16 + (lane >> 4) * 4;
    f32x4 p4 = *(const f32x4*)(pb2 + cb);
#pragma unroll
    for (int n = 0; n < 4; ++n) {
      int j = wc * 64 + n * 16 + (lane & 15);
      int col = col0 + j;
      const float* frow = FT32 + (size_t)idx_sh2[j] * CC;
#pragma unroll
      for (int r = 0; r < 4; ++r) {
        Vp[(size_t)(cb + r) * COLS + col] = acc[m][n][r] + p4[r] + frow[cb + r];
      }
    }
  }
}

// ---------------------------------------------------------------------------
// Kernel 4c: Z-GEMM (K=64): A1R = relu(s1*(W1p@h1 + Y1[n] - Y1[s]) + t1n),
// output [col][AH] fp16 via the verified LDS-transpose epilogue.
// Grid (COLS/128, AH/128).
// ---------------------------------------------------------------------------
__global__ __launch_bounds__(256) void zgemm_f16(
    int b, const _Float16* __restrict__ W1ph, const _Float16* __restrict__ h1g,
    const _Float16* __restrict__ Y1, const int* __restrict__ knn,
    const float* __restrict__ s1, const float* __restrict__ t1n,
    _Float16* __restrict__ A1Rp) {
  __shared__ char lds[34816];
  __shared__ int idx_sh2[128];
  char* As = lds;
  char* Bs = lds + 8192;
  const int t = threadIdx.x, lane = t & 63, w = t >> 6;
  const int wr = w >> 1, wc = w & 1;
  const int h0 = blockIdx.y * 128;
  const int col0 = blockIdx.x * 128;
  if (t < 128) idx_sh2[t] = knn[(size_t)b * COLS + col0 + t];
  f32x4 acc[4][4];
  f32x4 zz = {0.f, 0.f, 0.f, 0.f};
#pragma unroll
  for (int m = 0; m < 4; ++m)
#pragma unroll
    for (int n = 0; n < 4; ++n) acc[m][n] = zz;
#pragma unroll
  for (int s = 0; s < 2; ++s) {
    const int k0 = s * 32;
    stage_tile((const char*)(W1ph + (size_t)h0 * PH + k0), PH * 2, As, t);
    stage_tile((const char*)(h1g + (size_t)col0 * PH + k0), PH * 2, Bs, t);
    __syncthreads();
    half8 a[4], bf[4];
#pragma unroll
    for (int m = 0; m < 4; ++m) a[m] = frag_ld(As, wr * 64 + m * 16, lane);
#pragma unroll
    for (int n = 0; n < 4; ++n) bf[n] = frag_ld(Bs, wc * 64 + n * 16, lane);
#pragma unroll
    for (int m = 0; m < 4; ++m)
#pragma unroll
      for (int n = 0; n < 4; ++n)
        acc[m][n] = __builtin_amdgcn_mfma_f32_16x16x32_f16(a[m], bf[n], acc[m][n], 0, 0, 0);
    __syncthreads();
  }
  char* tb = lds + w * 8704;
#pragma unroll
  for (int m = 0; m < 4; ++m) {
    int hb = h0 + wr * 64 + m * 16 + (lane >> 4) * 4;
    f32x4 s4 = *(const f32x4*)(s1 + hb);
    f32x4 t4 = *(const f32x4*)(t1n + hb);
#pragma unroll
    for (int n = 0; n < 4; ++n) {
      int col_l = n * 16 + (lane & 15);
      int j = wc * 64 + col_l;
      int col = col0 + j;
      int sidx = idx_sh2[j];
      half4 yq4 = *(const half4*)(Y1 + (size_t)(col >> 4) * AH + hb);
      half4 ys4 = *(const half4*)(Y1 + (size_t)sidx * AH + hb);
      half4 p;
#pragma unroll
      for (int r = 0; r < 4; ++r) {
        float pre = acc[m][n][r] + (float)yq4[r] - (float)ys4[r];
        p[r] = (_Float16)fmaxf(pre * s4[r] + t4[r], 0.0f);
      }
      *(half4*)(tb + col_l * 136 + (m * 16 + (lane >> 4) * 4) * 2) = p;
    }
  }
  __syncthreads();
  char* dstbase = (char*)A1Rp + (size_t)(h0 + wr * 64) * 2;
#pragma unroll
  for (int pass = 0; pass < 8; ++pass) {
    int col_l = (lane >> 3) + pass * 8;
    int chunk = lane & 7;
    *(half8*)(dstbase + (size_t)(col0 + wc * 64 + col_l) * (AH * 2) + chunk * 16) =
        *(const half8*)(tb + col_l * 136 + chunk * 16);
  }
}

// ---------------------------------------------------------------------------
// Kernel 5: gemm2 = W2 @ A1R via f16 MFMA; fused softmax(K=16) + V-weighted
// sum. V read in [c][col] layout (verified round-4 pattern).
// ---------------------------------------------------------------------------
__global__ __launch_bounds__(256) void gemm2_f16(
    int b, const _Float16* __restrict__ Wh, const _Float16* __restrict__ A1Rp,
    const float* __restrict__ Vp, float* __restrict__ out) {
  __shared__ char lds[16384];
  char* As = lds;
  char* Bs = lds + 8192;
  const int t = threadIdx.x, lane = t & 63, w = t >> 6;
  const int wr = w >> 1, wc = w & 1;
  const int c0 = blockIdx.y * 128;
  const int col0 = blockIdx.x * 128;
  f32x4 acc[4][4];
  f32x4 zz = {0.f, 0.f, 0.f, 0.f};
#pragma unroll
  for (int m = 0; m < 4; ++m)
#pragma unroll
    for (int n = 0; n < 4; ++n) acc[m][n] = zz;
  for (int s = 0; s < AH / 32; ++s) {
    const int k0 = s * 32;
    stage_tile((const char*)(Wh + (size_t)c0 * AH + k0), AH * 2, As, t);
    stage_tile((const char*)(A1Rp + (size_t)col0 * AH + k0), AH * 2, Bs, t);
    __syncthreads();
    half8 a[4], bf[4];
#pragma unroll
    for (int m = 0; m < 4; ++m) a[m] = frag_ld(As, wr * 64 + m * 16, lane);
#pragma unroll
    for (int n = 0; n < 4; ++n) bf[n] = frag_ld(Bs, wc * 64 + n * 16, lane);
#pragma unroll
    for (int m = 0; m < 4; ++m)
#pragma unroll
      for (int n = 0; n < 4; ++n)
        acc[m][n] = __builtin_amdgcn_mfma_f32_16x16x32_f16(a[m], bf[n], acc[m][n], 0, 0, 0);
    __syncthreads();
  }
#pragma unroll
  for (int m = 0; m < 4; ++m)
#pragma unroll
    for (int n = 0; n < 4; ++n) {
      int cg2 = col0 + wc * 64 + n * 16 + (lane & 15);
      int nq = cg2 >> 4;
      int cbase = c0 + wr * 64 + m * 16 + (lane >> 4) * 4;
#pragma unroll
      for (int r = 0; r < 4; ++r) {
        float e = __expf(acc[m][n][r]);
        float se = e;
#pragma unroll
        for (int o = 8; o >= 1; o >>= 1) se += __shfl_xor(se, o);
        float vv = Vp[(size_t)(cbase + r) * COLS + cg2];
        float te = e * vv;
#pragma unroll
        for (int o = 8; o >= 1; o >>= 1) te += __shfl_xor(te, o);
        if ((lane & 15) == 0)
          out[((size_t)b * CC + cbase + r) * NN + nq] = __fdividef(te, se);
      }
    }
}

// ---------------------------------------------------------------------------
extern "C" void kernel_launch(void* const* d_in, const int* in_sizes, int n_in,
                              void* d_out, int out_size, void* d_ws, size_t ws_size,
                              hipStream_t stream) {
  const float* pcd     = (const float*)d_in[0];
  const float* feat    = (const float*)d_in[1];
  const float* pcd_fb  = (const float*)d_in[2];
  const float* feat_fb = (const float*)d_in[3];
  const float* pw1     = (const float*)d_in[4];
  const float* pb1     = (const float*)d_in[5];
  const float* pg      = (const float*)d_in[6];
  const float* pbeta   = (const float*)d_in[7];
  const float* pm      = (const float*)d_in[8];
  const float* pv      = (const float*)d_in[9];
  const float* pw2     = (const float*)d_in[10];
  const float* pb2     = (const float*)d_in[11];
  const float* aw1     = (const float*)d_in[12];
  const float* ab1     = (const float*)d_in[13];
  const float* ag      = (const float*)d_in[14];
  const float* abeta   = (const float*)d_in[15];
  const float* am      = (const float*)d_in[16];
  const float* av      = (const float*)d_in[17];
  const float* aw2     = (const float*)d_in[18];
  const float* ab2     = (const float*)d_in[19];
  (void)ab2;  // cancels in softmax
  float* out = (float*)d_out;

  char* ws = (char*)d_ws;
  size_t off = 0;
  int* idx_ws = (int*)(ws + off);         off += (size_t)BB * NN * KK * sizeof(int);
  _Float16* W1h = (_Float16*)(ws + off);  off += (size_t)AH * CC * 2;
  _Float16* W2h = (_Float16*)(ws + off);  off += (size_t)CC * AH * 2;
  _Float16* W1ph = (_Float16*)(ws + off); off += (size_t)AH * PH * 2;
  _Float16* pw2h = (_Float16*)(ws + off); off += (size_t)CC * PH * 2;
  float* s1 = (float*)(ws + off);         off += AH * sizeof(float);
  float* t1 = (float*)(ws + off);         off += AH * sizeof(float);
  float* t1n = (float*)(ws + off);        off += AH * sizeof(float);
  off = (off + 255) & ~(size_t)255;
  float* FT32 = (float*)(ws + off);       off += (size_t)SS * CC * 4;      //  4.2 MB
  _Float16* FT16 = (_Float16*)(ws + off); off += (size_t)SS * CC * 2;      //  2.1 MB
  _Float16* h1g = (_Float16*)(ws + off);  off += (size_t)COLS * PH * 2;    //  2.1 MB
  _Float16* Y1 = (_Float16*)(ws + off);   off += (size_t)SS * AH * 2;      //  4.2 MB
  _Float16* A1Rp = (_Float16*)(ws + off); off += (size_t)COLS * AH * 2;    // 33.6 MB
  float* Vp = (float*)(ws + off);         off += (size_t)COLS * CC * 4;    // 33.6 MB

  knn_kernel<<<dim3(BB * NN / 4), 256, 0, stream>>>(pcd, pcd_fb, idx_ws);
  repack<<<dim3(512), 256, 0, stream>>>(aw1, aw2, pw2, ag, abeta, am, av, ab1,
                                        W1h, W2h, pw2h, s1, t1);
  prep_w1p<<<dim3(AH), 64, 0, stream>>>(aw1, pw2, pb2, ab1, ag, abeta, am, av,
                                        W1ph, t1n);
  for (int b = 0; b < BB; ++b) {
    transpose_feat<<<dim3(256), 256, 0, stream>>>(b, feat, feat_fb, FT32, FT16);
    build_h1<<<dim3(NN / 4), 256, 0, stream>>>(
        b, pcd, pcd_fb, pw1, pb1, pg, pbeta, pm, pv, idx_ws, h1g);
    ygemm_f16<<<dim3(SS / 128, AH / 128), 256, 0, stream>>>(W1h, FT16, Y1);
    pegemm_f16<<<dim3(COLS / 128, CC / 128), 256, 0, stream>>>(
        b, pw2h, h1g, FT32, pb2, idx_ws, Vp);
    zgemm_f16<<<dim3(COLS / 128, AH / 128), 256, 0, stream>>>(
        b, W1ph, h1g, Y1, idx_ws, s1, t1n, A1Rp);
    gemm2_f16<<<dim3(COLS / 128, CC / 128), 256, 0, stream>>>(b, W2h, A1Rp, Vp, out);
  }
}

// Round 12
// 791.980 us; speedup vs baseline: 1.3822x; 1.2758x over previous
//
#include <hip/hip_runtime.h>
#include <math.h>

#define BB 8
#define NN 1024
#define MM 1024
#define CC 512
#define SS 2048
#define KK 16
#define PH 64
#define AH 1024
#define COLS (NN * KK)
#define EPSV 1e-5f

typedef _Float16 half8 __attribute__((ext_vector_type(8)));
typedef _Float16 half4 __attribute__((ext_vector_type(4)));
typedef float f32x4 __attribute__((ext_vector_type(4)));

// ---------------------------------------------------------------------------
// global->LDS direct copy, 16B per lane. Dest is wave-uniform base + lane*16.
// ---------------------------------------------------------------------------
__device__ __forceinline__ void gl_lds16(const void* g, void* l) {
  __builtin_amdgcn_global_load_lds(
      (const __attribute__((address_space(1))) unsigned int*)g,
      (__attribute__((address_space(3))) unsigned int*)l, 16, 0, 0);
}

// Involution swizzle on LDS byte offsets: XOR bits 4-5 with bits 7-8.
__device__ __forceinline__ int swz(int x) { return x ^ (((x >> 7) & 3) << 4); }

// Stage a 128-row x 64-byte (8KB) tile into `region` (linear LDS dest,
// pre-swizzled per-lane global source so that reads with swz() see logical).
__device__ __forceinline__ void stage_tile(const char* gbase, size_t row_stride,
                                           char* region, int t) {
  const int lane = t & 63, w = t >> 6;
#pragma unroll
  for (int pass = 0; pass < 2; ++pass) {
    int d = pass * 4096 + w * 1024 + lane * 16;
    int l = swz(d);
    gl_lds16(gbase + (size_t)(l >> 6) * row_stride + (l & 63),
             region + pass * 4096 + w * 1024);
  }
}

__device__ __forceinline__ half8 frag_ld(const char* region, int rowbase, int lane) {
  int lb = (rowbase + (lane & 15)) * 64 + (lane >> 4) * 16;
  return *(const half8*)(region + swz(lb));
}

// ---------------------------------------------------------------------------
// Kernel 1: KNN (unchanged — verified).
// ---------------------------------------------------------------------------
__global__ __launch_bounds__(256) void knn_kernel(
    const float* __restrict__ pcd, const float* __restrict__ pcd_fb,
    int* __restrict__ knn) {
  __shared__ float sx[SS], sy[SS], sz[SS], ss[SS];
  const int t = threadIdx.x;
  const int b = blockIdx.x >> 8;
  const int nbase = (blockIdx.x & 255) * 4;
  for (int s = t; s < SS; s += 256) {
    float x, y, z;
    if (s < NN) {
      x = pcd[(b * 3 + 0) * NN + s];
      y = pcd[(b * 3 + 1) * NN + s];
      z = pcd[(b * 3 + 2) * NN + s];
    } else {
      int s2 = s - NN;
      x = pcd_fb[(b * 3 + 0) * MM + s2];
      y = pcd_fb[(b * 3 + 1) * MM + s2];
      z = pcd_fb[(b * 3 + 2) * MM + s2];
    }
    sx[s] = x; sy[s] = y; sz[s] = z;
    ss[s] = x * x + y * y + z * z;
  }
  __syncthreads();
  const int wv = t >> 6, lane = t & 63;
  const int n = nbase + wv;
  const float qx = sx[n], qy = sy[n], qz = sz[n];
  const float qq = qx * qx + qy * qy + qz * qz;
  float d[32];
#pragma unroll
  for (int i = 0; i < 32; ++i) {
    int s = i * 64 + lane;
    d[i] = qq - 2.0f * (qx * sx[s] + qy * sy[s] + qz * sz[s]) + ss[s];
  }
  unsigned mask = 0;
  int win = -1;
#pragma unroll
  for (int r = 0; r < 16; ++r) {
    float best = 3.4e38f;
    int bi = 0x7fffffff;
#pragma unroll
    for (int i = 0; i < 32; ++i) {
      if (!((mask >> i) & 1) && d[i] < best) { best = d[i]; bi = i * 64 + lane; }
    }
#pragma unroll
    for (int off = 32; off >= 1; off >>= 1) {
      float ov = __shfl_xor(best, off);
      int oi = __shfl_xor(bi, off);
      if (ov < best || (ov == best && oi < bi)) { best = ov; bi = oi; }
    }
    if ((bi & 63) == lane) mask |= 1u << (bi >> 6);
    if (lane == r) win = bi;
  }
  if (lane < 16) knn[((size_t)b * NN + n) * KK + lane] = win;
}

// ---------------------------------------------------------------------------
// Kernel 2: fused repack (blocks 0..511) + prep_w1p (blocks 512..767).
// repack: W1,W2,pos_w2 -> fp16; s1 = bn scale.
// prep: W1p = W1@pos_w2 (fp16), t1n = (b1 + W1@pos_b2 - m)*s1 + beta.
// ---------------------------------------------------------------------------
__global__ __launch_bounds__(256) void repack_prep(
    const float* __restrict__ aw1, const float* __restrict__ aw2,
    const float* __restrict__ pw2, const float* __restrict__ pb2,
    const float* __restrict__ ag, const float* __restrict__ abeta,
    const float* __restrict__ am, const float* __restrict__ av,
    const float* __restrict__ ab1,
    _Float16* __restrict__ w1h, _Float16* __restrict__ w2h,
    _Float16* __restrict__ pw2h, _Float16* __restrict__ W1ph,
    float* __restrict__ s1, float* __restrict__ t1n) {
  const int t = threadIdx.x;
  __shared__ float wrow4[4][CC];
  if (blockIdx.x < 512) {
    int i = blockIdx.x * 256 + t;
    for (int e = i; e < AH * CC; e += 512 * 256) w1h[e] = (_Float16)aw1[e];
    for (int e = i; e < CC * AH; e += 512 * 256) w2h[e] = (_Float16)aw2[e];
    for (int e = i; e < CC * PH; e += 512 * 256) pw2h[e] = (_Float16)pw2[e];
    if (i < AH) s1[i] = ag[i] * rsqrtf(av[i] + EPSV);
  } else {
    const int wv = t >> 6, lane = t & 63;
    const int h = (blockIdx.x - 512) * 4 + wv;
    for (int c = lane; c < CC; c += 64) wrow4[wv][c] = aw1[(size_t)h * CC + c];
    __syncthreads();
    float acc = 0.0f;
    for (int c = 0; c < CC; ++c) acc += wrow4[wv][c] * pw2[(size_t)c * PH + lane];
    W1ph[(size_t)h * PH + lane] = (_Float16)acc;
    float c1p = 0.0f;
    for (int c = lane; c < CC; c += 64) c1p += wrow4[wv][c] * pb2[c];
#pragma unroll
    for (int o = 32; o >= 1; o >>= 1) c1p += __shfl_xor(c1p, o);
    if (lane == 0) {
      float sc = ag[h] * rsqrtf(av[h] + EPSV);
      t1n[h] = (ab1[h] + c1p - am[h]) * sc + abeta[h];
    }
  }
}

// ---------------------------------------------------------------------------
// Kernel 3: fused batch-wide transpose (blocks 0..2047) + build_h1
// (blocks 2048..4095). Transpose: fusion_feat [c][s] -> FT16 [s][c] fp16.
// build_h1: pos MLP layer1+BN+ReLU -> h1g [col][64] fp16. One dispatch.
// ---------------------------------------------------------------------------
__global__ __launch_bounds__(256) void trans_h1(
    const float* __restrict__ feat, const float* __restrict__ feat_fb,
    const float* __restrict__ pcd, const float* __restrict__ pcd_fb,
    const float* __restrict__ pw1, const float* __restrict__ pb1,
    const float* __restrict__ pg, const float* __restrict__ pbeta,
    const float* __restrict__ pm, const float* __restrict__ pv,
    const int* __restrict__ knn,
    _Float16* __restrict__ FT16all, _Float16* __restrict__ h1gall) {
  const int t = threadIdx.x;
  __shared__ float tl[64][65];
  __shared__ float prel_s[4][3][KK];
  __shared__ int idx_s[4][KK];
  if (blockIdx.x < 2048) {
    const int b = blockIdx.x >> 8, blk = blockIdx.x & 255;
    const int s0 = (blk & 31) * 64, c0 = (blk >> 5) * 64;
    const float* src = (s0 < NN) ? feat + (size_t)b * CC * NN + s0
                                 : feat_fb + (size_t)b * CC * MM + (s0 - NN);
    const int sl = t & 63, w4 = t >> 6;
#pragma unroll
    for (int r = 0; r < 16; ++r) {
      int cl = w4 * 16 + r;
      tl[sl][cl] = src[(size_t)(c0 + cl) * NN + sl];
    }
    __syncthreads();
    _Float16* FT = FT16all + (size_t)b * SS * CC;
#pragma unroll
    for (int r = 0; r < 16; ++r) {
      int sl2 = w4 * 16 + r;
      FT[((size_t)s0 + sl2) * CC + c0 + sl] = (_Float16)tl[sl2][sl];
    }
  } else {
    const int bid = blockIdx.x - 2048;
    const int b = bid >> 8, nb = bid & 255;
    const int wv = t >> 6, lane = t & 63;
    const int n = nb * 4 + wv;
    if (lane < KK) idx_s[wv][lane] = knn[(size_t)b * COLS + n * KK + lane];
    __syncthreads();
    if (lane < 48) {
      int dd = lane >> 4, k = lane & 15;
      int s = idx_s[wv][k];
      float gp = (s < NN) ? pcd[(b * 3 + dd) * NN + s]
                          : pcd_fb[(b * 3 + dd) * MM + (s - NN)];
      prel_s[wv][dd][k] = pcd[(b * 3 + dd) * NN + n] - gp;
    }
    __syncthreads();
    const int h = lane;
    const float w0 = pw1[h * 3 + 0], w1v = pw1[h * 3 + 1], w2v = pw1[h * 3 + 2];
    const float sc = pg[h] * rsqrtf(pv[h] + EPSV);
    const float sh = (pb1[h] - pm[h]) * sc + pbeta[h];
    _Float16* h1g = h1gall + (size_t)b * COLS * PH;
#pragma unroll
    for (int k = 0; k < KK; ++k) {
      float val = w0 * prel_s[wv][0][k] + w1v * prel_s[wv][1][k]
                + w2v * prel_s[wv][2][k];
      h1g[((size_t)n * KK + k) * PH + h] = (_Float16)fmaxf(val * sc + sh, 0.0f);
    }
  }
}

// ---------------------------------------------------------------------------
// Kernel 4: batch-wide Y-GEMM: Y1[b] = W1 @ fusion_feat[b], [s][AH] fp16 via
// the verified LDS-transpose epilogue. Grid (8*16, AH/128) — one dispatch.
// ---------------------------------------------------------------------------
__global__ __launch_bounds__(256) void ygemm_f16(
    const _Float16* __restrict__ Wh, const _Float16* __restrict__ FT16all,
    _Float16* __restrict__ Y1all) {
  __shared__ char lds[34816];
  char* As = lds;
  char* Bs = lds + 8192;
  const int t = threadIdx.x, lane = t & 63, w = t >> 6;
  const int wr = w >> 1, wc = w & 1;
  const int b = blockIdx.x >> 4;
  const int col0 = (blockIdx.x & 15) * 128;
  const int h0 = blockIdx.y * 128;
  const _Float16* FT16 = FT16all + (size_t)b * SS * CC;
  _Float16* Y1 = Y1all + (size_t)b * SS * AH;
  f32x4 acc[4][4];
  f32x4 zz = {0.f, 0.f, 0.f, 0.f};
#pragma unroll
  for (int m = 0; m < 4; ++m)
#pragma unroll
    for (int n = 0; n < 4; ++n) acc[m][n] = zz;
  for (int s = 0; s < CC / 32; ++s) {
    const int k0 = s * 32;
    stage_tile((const char*)(Wh + (size_t)h0 * CC + k0), CC * 2, As, t);
    stage_tile((const char*)(FT16 + (size_t)col0 * CC + k0), CC * 2, Bs, t);
    __syncthreads();
    half8 a[4], bf[4];
#pragma unroll
    for (int m = 0; m < 4; ++m) a[m] = frag_ld(As, wr * 64 + m * 16, lane);
#pragma unroll
    for (int n = 0; n < 4; ++n) bf[n] = frag_ld(Bs, wc * 64 + n * 16, lane);
#pragma unroll
    for (int m = 0; m < 4; ++m)
#pragma unroll
      for (int n = 0; n < 4; ++n)
        acc[m][n] = __builtin_amdgcn_mfma_f32_16x16x32_f16(a[m], bf[n], acc[m][n], 0, 0, 0);
    __syncthreads();
  }
  char* tb = lds + w * 8704;
#pragma unroll
  for (int m = 0; m < 4; ++m) {
#pragma unroll
    for (int n = 0; n < 4; ++n) {
      half4 p;
#pragma unroll
      for (int r = 0; r < 4; ++r) p[r] = (_Float16)acc[m][n][r];
      int col_l = n * 16 + (lane & 15);
      *(half4*)(tb + col_l * 136 + (m * 16 + (lane >> 4) * 4) * 2) = p;
    }
  }
  __syncthreads();
  char* dstbase = (char*)Y1 + (size_t)(h0 + wr * 64) * 2;
#pragma unroll
  for (int pass = 0; pass < 8; ++pass) {
    int col_l = (lane >> 3) + pass * 8;
    int chunk = lane & 7;
    *(half8*)(dstbase + (size_t)(col0 + wc * 64 + col_l) * (AH * 2) + chunk * 16) =
        *(const half8*)(tb + col_l * 136 + chunk * 16);
  }
}

// ---------------------------------------------------------------------------
// Kernel 5: fused PE+Z GEMM (per batch). blockIdx.y<4: V-path
// (V[c][col] fp16 = pw2@h1 + pb2 + FT16[s][c]); else Z-path
// (A1R = relu(s1*(W1p@h1 + Y1[n]-Y1[s]) + t1n), transpose epilogue).
// Grid (COLS/128, 12).
// ---------------------------------------------------------------------------
__global__ __launch_bounds__(256) void pz_f16(
    const _Float16* __restrict__ pw2h, const _Float16* __restrict__ W1ph,
    const _Float16* __restrict__ h1g, const _Float16* __restrict__ FT16,
    const _Float16* __restrict__ Y1, const int* __restrict__ knn_b,
    const float* __restrict__ pb2, const float* __restrict__ s1,
    const float* __restrict__ t1n,
    _Float16* __restrict__ Vh, _Float16* __restrict__ A1Rp) {
  __shared__ char lds[34816];
  __shared__ int idx_sh2[128];
  char* As = lds;
  char* Bs = lds + 8192;
  const int t = threadIdx.x, lane = t & 63, w = t >> 6;
  const int wr = w >> 1, wc = w & 1;
  const bool pe = (blockIdx.y < 4);
  const int r0 = pe ? blockIdx.y * 128 : (blockIdx.y - 4) * 128;
  const int col0 = blockIdx.x * 128;
  if (t < 128) idx_sh2[t] = knn_b[col0 + t];
  const _Float16* Abase = (pe ? pw2h : W1ph) + (size_t)r0 * PH;
  f32x4 acc[4][4];
  f32x4 zz = {0.f, 0.f, 0.f, 0.f};
#pragma unroll
  for (int m = 0; m < 4; ++m)
#pragma unroll
    for (int n = 0; n < 4; ++n) acc[m][n] = zz;
#pragma unroll
  for (int s = 0; s < 2; ++s) {
    const int k0 = s * 32;
    stage_tile((const char*)(Abase + k0), PH * 2, As, t);
    stage_tile((const char*)(h1g + (size_t)col0 * PH + k0), PH * 2, Bs, t);
    __syncthreads();
    half8 a[4], bf[4];
#pragma unroll
    for (int m = 0; m < 4; ++m) a[m] = frag_ld(As, wr * 64 + m * 16, lane);
#pragma unroll
    for (int n = 0; n < 4; ++n) bf[n] = frag_ld(Bs, wc * 64 + n * 16, lane);
#pragma unroll
    for (int m = 0; m < 4; ++m)
#pragma unroll
      for (int n = 0; n < 4; ++n)
        acc[m][n] = __builtin_amdgcn_mfma_f32_16x16x32_f16(a[m], bf[n], acc[m][n], 0, 0, 0);
    __syncthreads();
  }
  if (pe) {
#pragma unroll
    for (int m = 0; m < 4; ++m) {
      int cb = r0 + wr * 64 + m * 16 + (lane >> 4) * 4;
      f32x4 p4 = *(const f32x4*)(pb2 + cb);
#pragma unroll
      for (int n = 0; n < 4; ++n) {
        int j = wc * 64 + n * 16 + (lane & 15);
        int col = col0 + j;
        const _Float16* frow = FT16 + (size_t)idx_sh2[j] * CC;
#pragma unroll
        for (int r = 0; r < 4; ++r) {
          Vh[(size_t)(cb + r) * COLS + col] =
              (_Float16)(acc[m][n][r] + p4[r] + (float)frow[cb + r]);
        }
      }
    }
  } else {
    char* tb = lds + w * 8704;
#pragma unroll
    for (int m = 0; m < 4; ++m) {
      int hb = r0 + wr * 64 + m * 16 + (lane >> 4) * 4;
      f32x4 s4 = *(const f32x4*)(s1 + hb);
      f32x4 t4 = *(const f32x4*)(t1n + hb);
#pragma unroll
      for (int n = 0; n < 4; ++n) {
        int col_l = n * 16 + (lane & 15);
        int j = wc * 64 + col_l;
        int col = col0 + j;
        int sidx = idx_sh2[j];
        half4 yq4 = *(const half4*)(Y1 + (size_t)(col >> 4) * AH + hb);
        half4 ys4 = *(const half4*)(Y1 + (size_t)sidx * AH + hb);
        half4 p;
#pragma unroll
        for (int r = 0; r < 4; ++r) {
          float pre = acc[m][n][r] + (float)yq4[r] - (float)ys4[r];
          p[r] = (_Float16)fmaxf(pre * s4[r] + t4[r], 0.0f);
        }
        *(half4*)(tb + col_l * 136 + (m * 16 + (lane >> 4) * 4) * 2) = p;
      }
    }
    __syncthreads();
    char* dstbase = (char*)A1Rp + (size_t)(r0 + wr * 64) * 2;
#pragma unroll
    for (int pass = 0; pass < 8; ++pass) {
      int col_l = (lane >> 3) + pass * 8;
      int chunk = lane & 7;
      *(half8*)(dstbase + (size_t)(col0 + wc * 64 + col_l) * (AH * 2) + chunk * 16) =
          *(const half8*)(tb + col_l * 136 + chunk * 16);
    }
  }
}

// ---------------------------------------------------------------------------
// Kernel 6: gemm2 = W2 @ A1R via f16 MFMA; fused softmax(K=16) + V-weighted
// sum. V fp16 [c][col]. (structure verified; only V dtype changed)
// ---------------------------------------------------------------------------
__global__ __launch_bounds__(256) void gemm2_f16(
    int b, const _Float16* __restrict__ Wh, const _Float16* __restrict__ A1Rp,
    const _Float16* __restrict__ Vh, float* __restrict__ out) {
  __shared__ char lds[16384];
  char* As = lds;
  char* Bs = lds + 8192;
  const int t = threadIdx.x, lane = t & 63, w = t >> 6;
  const int wr = w >> 1, wc = w & 1;
  const int c0 = blockIdx.y * 128;
  const int col0 = blockIdx.x * 128;
  f32x4 acc[4][4];
  f32x4 zz = {0.f, 0.f, 0.f, 0.f};
#pragma unroll
  for (int m = 0; m < 4; ++m)
#pragma unroll
    for (int n = 0; n < 4; ++n) acc[m][n] = zz;
  for (int s = 0; s < AH / 32; ++s) {
    const int k0 = s * 32;
    stage_tile((const char*)(Wh + (size_t)c0 * AH + k0), AH * 2, As, t);
    stage_tile((const char*)(A1Rp + (size_t)col0 * AH + k0), AH * 2, Bs, t);
    __syncthreads();
    half8 a[4], bf[4];
#pragma unroll
    for (int m = 0; m < 4; ++m) a[m] = frag_ld(As, wr * 64 + m * 16, lane);
#pragma unroll
    for (int n = 0; n < 4; ++n) bf[n] = frag_ld(Bs, wc * 64 + n * 16, lane);
#pragma unroll
    for (int m = 0; m < 4; ++m)
#pragma unroll
      for (int n = 0; n < 4; ++n)
        acc[m][n] = __builtin_amdgcn_mfma_f32_16x16x32_f16(a[m], bf[n], acc[m][n], 0, 0, 0);
    __syncthreads();
  }
#pragma unroll
  for (int m = 0; m < 4; ++m)
#pragma unroll
    for (int n = 0; n < 4; ++n) {
      int cg2 = col0 + wc * 64 + n * 16 + (lane & 15);
      int nq = cg2 >> 4;
      int cbase = c0 + wr * 64 + m * 16 + (lane >> 4) * 4;
#pragma unroll
      for (int r = 0; r < 4; ++r) {
        float e = __expf(acc[m][n][r]);
        float se = e;
#pragma unroll
        for (int o = 8; o >= 1; o >>= 1) se += __shfl_xor(se, o);
        float vv = (float)Vh[(size_t)(cbase + r) * COLS + cg2];
        float te = e * vv;
#pragma unroll
        for (int o = 8; o >= 1; o >>= 1) te += __shfl_xor(te, o);
        if ((lane & 15) == 0)
          out[((size_t)b * CC + cbase + r) * NN + nq] = __fdividef(te, se);
      }
    }
}

// ---------------------------------------------------------------------------
extern "C" void kernel_launch(void* const* d_in, const int* in_sizes, int n_in,
                              void* d_out, int out_size, void* d_ws, size_t ws_size,
                              hipStream_t stream) {
  const float* pcd     = (const float*)d_in[0];
  const float* feat    = (const float*)d_in[1];
  const float* pcd_fb  = (const float*)d_in[2];
  const float* feat_fb = (const float*)d_in[3];
  const float* pw1     = (const float*)d_in[4];
  const float* pb1     = (const float*)d_in[5];
  const float* pg      = (const float*)d_in[6];
  const float* pbeta   = (const float*)d_in[7];
  const float* pm      = (const float*)d_in[8];
  const float* pv      = (const float*)d_in[9];
  const float* pw2     = (const float*)d_in[10];
  const float* pb2     = (const float*)d_in[11];
  const float* aw1     = (const float*)d_in[12];
  const float* ab1     = (const float*)d_in[13];
  const float* ag      = (const float*)d_in[14];
  const float* abeta   = (const float*)d_in[15];
  const float* am      = (const float*)d_in[16];
  const float* av      = (const float*)d_in[17];
  const float* aw2     = (const float*)d_in[18];
  const float* ab2     = (const float*)d_in[19];
  (void)ab2;  // cancels in softmax
  float* out = (float*)d_out;

  char* ws = (char*)d_ws;
  size_t off = 0;
  int* idx_ws = (int*)(ws + off);         off += (size_t)BB * NN * KK * sizeof(int);
  _Float16* W1h = (_Float16*)(ws + off);  off += (size_t)AH * CC * 2;
  _Float16* W2h = (_Float16*)(ws + off);  off += (size_t)CC * AH * 2;
  _Float16* W1ph = (_Float16*)(ws + off); off += (size_t)AH * PH * 2;
  _Float16* pw2h = (_Float16*)(ws + off); off += (size_t)CC * PH * 2;
  float* s1 = (float*)(ws + off);         off += AH * sizeof(float);
  float* t1n = (float*)(ws + off);        off += AH * sizeof(float);
  off = (off + 255) & ~(size_t)255;
  _Float16* FT16all = (_Float16*)(ws + off); off += (size_t)BB * SS * CC * 2;   // 16.8 MB
  _Float16* h1gall = (_Float16*)(ws + off);  off += (size_t)BB * COLS * PH * 2; // 16.8 MB
  _Float16* Y1all = (_Float16*)(ws + off);   off += (size_t)BB * SS * AH * 2;   // 33.6 MB
  _Float16* A1Rp = (_Float16*)(ws + off);    off += (size_t)COLS * AH * 2;      // 33.6 MB
  _Float16* Vh = (_Float16*)(ws + off);      off += (size_t)COLS * CC * 2;      // 16.8 MB
  // total ~120 MB < proven >=134.7 MB

  knn_kernel<<<dim3(BB * NN / 4), 256, 0, stream>>>(pcd, pcd_fb, idx_ws);
  repack_prep<<<dim3(768), 256, 0, stream>>>(
      aw1, aw2, pw2, pb2, ag, abeta, am, av, ab1,
      W1h, W2h, pw2h, W1ph, s1, t1n);
  trans_h1<<<dim3(4096), 256, 0, stream>>>(
      feat, feat_fb, pcd, pcd_fb, pw1, pb1, pg, pbeta, pm, pv, idx_ws,
      FT16all, h1gall);
  ygemm_f16<<<dim3(BB * (SS / 128), AH / 128), 256, 0, stream>>>(
      W1h, FT16all, Y1all);
  for (int b = 0; b < BB; ++b) {
    const _Float16* FT16 = FT16all + (size_t)b * SS * CC;
    const _Float16* h1g = h1gall + (size_t)b * COLS * PH;
    const _Float16* Y1 = Y1all + (size_t)b * SS * AH;
    const int* knn_b = idx_ws + (size_t)b * COLS;
    pz_f16<<<dim3(COLS / 128, 12), 256, 0, stream>>>(
        pw2h, W1ph, h1g, FT16, Y1, knn_b, pb2, s1, t1n, Vh, A1Rp);
    gemm2_f16<<<dim3(COLS / 128, CC / 128), 256, 0, stream>>>(
        b, W2h, A1Rp, Vh, out);
  }
}